// Round 1
// 1294.403 us; speedup vs baseline: 1.6579x; 1.6579x over previous
//
#include <hip/hip_runtime.h>
#include <math.h>

// Problem constants: B=4, H=384, W=1280, NUM=8, IDX_REF=4
static constexpr int B_ = 4;
static constexpr int H_ = 384;
static constexpr int W_ = 1280;
static constexpr int HW_ = H_ * W_;

typedef _Float16 f16x8 __attribute__((ext_vector_type(8)));
typedef float f32x4 __attribute__((ext_vector_type(4)));

// ---------------------------------------------------------------------------
// Guidance band = [normal(3), left(3), right(3), warp(right)-left(3)]
// layout (g, 12, rows, W) covering global rows [y0g, y0g+rows)
// ---------------------------------------------------------------------------
__global__ __launch_bounds__(256) void guidance_band(
    const float* __restrict__ disp, const float* __restrict__ normal,
    const float* __restrict__ left, const float* __restrict__ right,
    float* __restrict__ guid, int b0, int g, int y0g, int rows)
{
  int idx = blockIdx.x * 256 + threadIdx.x;
  if (idx >= g * rows * W_) return;
  int x = idx % W_;
  int t = idx / W_;
  int yr = t % rows;
  int gi = t / rows;
  int y = y0g + yr;
  int b = b0 + gi;
  int p = y * W_ + x;

  float d = disp[(size_t)b * HW_ + p];
  float xs = (float)x - d;
  float x0f = floorf(xs);
  int x0 = (int)x0f;
  float w1 = xs - x0f;
  int xi0 = x0, xi1 = x0 + 1;
  float v0 = (xi0 >= 0 && xi0 < W_) ? 1.f : 0.f;
  float v1 = (xi1 >= 0 && xi1 < W_) ? 1.f : 0.f;
  int xc0 = min(max(xi0, 0), W_ - 1);
  int xc1 = min(max(xi1, 0), W_ - 1);
  float w0f = (1.f - w1) * v0;
  float w1f = w1 * v1;

#pragma unroll
  for (int c = 0; c < 3; c++) {
    const float* rrow = right + (size_t)(b * 3 + c) * HW_ + (size_t)y * W_;
    float l = left[(size_t)(b * 3 + c) * HW_ + p];
    float n = normal[(size_t)(b * 3 + c) * HW_ + p];
    float r = rrow[x];
    float warped = w0f * rrow[xc0] + w1f * rrow[xc1];
    size_t base = ((size_t)gi * 12) * rows * W_ + (size_t)yr * W_ + x;
    size_t cs = (size_t)rows * W_;
    guid[base + (size_t)c * cs]       = n;
    guid[base + (size_t)(3 + c) * cs] = l;
    guid[base + (size_t)(6 + c) * cs] = r;
    guid[base + (size_t)(9 + c) * cs] = warped - l;
  }
}

// ---------------------------------------------------------------------------
// VALU banded 3x3 conv (retained for conv1 only: C_IN=12 is MFMA-K-unfriendly
// and conv1 is ~10% of conv FLOPs). See R8/R10 notes.
// ---------------------------------------------------------------------------
#define CONV_CO4(CO, A00, A01, A10, A11)                                       \
  {                                                                            \
    const float* wp = wgt + ((size_t)(co0 + (CO)) * C_IN + ci) * 9;            \
    float w0 = wp[0], w1 = wp[1], w2 = wp[2], w3 = wp[3], w4 = wp[4];          \
    float w5 = wp[5], w6 = wp[6], w7 = wp[7], w8 = wp[8];                      \
    A00 = fmaf(i00, w0, A00); A00 = fmaf(i01, w1, A00); A00 = fmaf(i02, w2, A00); \
    A00 = fmaf(i10, w3, A00); A00 = fmaf(i11, w4, A00); A00 = fmaf(i12, w5, A00); \
    A00 = fmaf(i20, w6, A00); A00 = fmaf(i21, w7, A00); A00 = fmaf(i22, w8, A00); \
    A01 = fmaf(i01, w0, A01); A01 = fmaf(i02, w1, A01); A01 = fmaf(i03, w2, A01); \
    A01 = fmaf(i11, w3, A01); A01 = fmaf(i12, w4, A01); A01 = fmaf(i13, w5, A01); \
    A01 = fmaf(i21, w6, A01); A01 = fmaf(i22, w7, A01); A01 = fmaf(i23, w8, A01); \
    A10 = fmaf(i10, w0, A10); A10 = fmaf(i11, w1, A10); A10 = fmaf(i12, w2, A10); \
    A10 = fmaf(i20, w3, A10); A10 = fmaf(i21, w4, A10); A10 = fmaf(i22, w5, A10); \
    A10 = fmaf(i30, w6, A10); A10 = fmaf(i31, w7, A10); A10 = fmaf(i32, w8, A10); \
    A11 = fmaf(i11, w0, A11); A11 = fmaf(i12, w1, A11); A11 = fmaf(i13, w2, A11); \
    A11 = fmaf(i21, w3, A11); A11 = fmaf(i22, w4, A11); A11 = fmaf(i23, w5, A11); \
    A11 = fmaf(i31, w6, A11); A11 = fmaf(i32, w7, A11); A11 = fmaf(i33, w8, A11); \
  }

template <int C_IN, int C_OUT, int CHUNK, bool BNRELU>
__global__ __launch_bounds__(256, 8) void conv3x3_px4(
    const float* __restrict__ in, const float* __restrict__ wgt,
    const float* __restrict__ bn_g, const float* __restrict__ bn_b,
    const float* __restrict__ bn_m, const float* __restrict__ bn_v,
    float* __restrict__ out,
    int in_y0, int in_rows, int out_y0, int out_rows)
{
  constexpr int TX = 32, TY = 32;
  static_assert(C_IN % CHUNK == 0, "chunking");
  static_assert(C_OUT % 8 == 0, "co tiling");
  constexpr int NCO = C_OUT / 8;
  constexpr int LH = TY + 2;      // 34
  constexpr int LWS = 36;         // 34 used + 2 pad; 16B-aligned rows
  constexpr int QPC = LH * 9;     // 306 quads per channel tile

  __shared__ float smem[CHUNK][LH][LWS];

  const int tilesX = W_ / TX;     // 40
  const int tilesY = (out_rows + TY - 1) / TY;
  int t = blockIdx.x;
  int coi = t % NCO;  t /= NCO;    // coi FASTEST: co-siblings share L3 tile
  int txi = t % tilesX; t /= tilesX;
  int tyi = t % tilesY;
  int gi  = t / tilesY;
  const int x0  = txi * TX;
  const int oy0 = out_y0 + tyi * TY;
  const int co0 = coi * 8;

  const int tid = threadIdx.x;
  const int lx2 = (tid & 15) * 2;   // cols lx2, lx2+1
  const int ly2 = (tid >> 4) * 2;   // rows ly2, ly2+1

  float a0_00 = 0.f, a0_01 = 0.f, a0_10 = 0.f, a0_11 = 0.f;
  float a1_00 = 0.f, a1_01 = 0.f, a1_10 = 0.f, a1_11 = 0.f;
  float a2_00 = 0.f, a2_01 = 0.f, a2_10 = 0.f, a2_11 = 0.f;
  float a3_00 = 0.f, a3_01 = 0.f, a3_10 = 0.f, a3_11 = 0.f;
  float a4_00 = 0.f, a4_01 = 0.f, a4_10 = 0.f, a4_11 = 0.f;
  float a5_00 = 0.f, a5_01 = 0.f, a5_10 = 0.f, a5_11 = 0.f;
  float a6_00 = 0.f, a6_01 = 0.f, a6_10 = 0.f, a6_11 = 0.f;
  float a7_00 = 0.f, a7_01 = 0.f, a7_10 = 0.f, a7_11 = 0.f;

  for (int c0 = 0; c0 < C_IN; c0 += CHUNK) {
    for (int i = tid; i < CHUNK * QPC; i += 256) {
      int c  = i / QPC;
      int r  = i - c * QPC;
      int yy = r / 9;
      int q  = r - yy * 9;
      int gy = oy0 + yy - 1;
      int by = gy - in_y0;
      int gx = x0 + 4 * q - 1;
      float v0 = 0.f, v1 = 0.f, v2 = 0.f, v3 = 0.f;
      if ((unsigned)by < (unsigned)in_rows) {
        const float* src = in + ((size_t)(gi * C_IN + c0 + c) * in_rows + by) * W_;
        v0 = ((unsigned)(gx + 0) < (unsigned)W_) ? src[gx + 0] : 0.f;
        v1 = ((unsigned)(gx + 1) < (unsigned)W_) ? src[gx + 1] : 0.f;
        v2 = ((unsigned)(gx + 2) < (unsigned)W_) ? src[gx + 2] : 0.f;
        v3 = ((unsigned)(gx + 3) < (unsigned)W_) ? src[gx + 3] : 0.f;
      }
      float* dst = &smem[c][yy][4 * q];
      dst[0] = v0; dst[1] = v1; dst[2] = v2; dst[3] = v3;
    }
    __syncthreads();

    for (int c = 0; c < CHUNK; c++) {
      const float* r0p = &smem[c][ly2 + 0][lx2];
      const float* r1p = &smem[c][ly2 + 1][lx2];
      const float* r2p = &smem[c][ly2 + 2][lx2];
      const float* r3p = &smem[c][ly2 + 3][lx2];
      float2 p00 = *(const float2*)(r0p), p01 = *(const float2*)(r0p + 2);
      float2 p10 = *(const float2*)(r1p), p11 = *(const float2*)(r1p + 2);
      float2 p20 = *(const float2*)(r2p), p21 = *(const float2*)(r2p + 2);
      float2 p30 = *(const float2*)(r3p), p31 = *(const float2*)(r3p + 2);
      float i00 = p00.x, i01 = p00.y, i02 = p01.x, i03 = p01.y;
      float i10 = p10.x, i11 = p10.y, i12 = p11.x, i13 = p11.y;
      float i20 = p20.x, i21 = p20.y, i22 = p21.x, i23 = p21.y;
      float i30 = p30.x, i31 = p30.y, i32 = p31.x, i33 = p31.y;
      const int ci = c0 + c;
      CONV_CO4(0, a0_00, a0_01, a0_10, a0_11)
      CONV_CO4(1, a1_00, a1_01, a1_10, a1_11)
      CONV_CO4(2, a2_00, a2_01, a2_10, a2_11)
      CONV_CO4(3, a3_00, a3_01, a3_10, a3_11)
      CONV_CO4(4, a4_00, a4_01, a4_10, a4_11)
      CONV_CO4(5, a5_00, a5_01, a5_10, a5_11)
      CONV_CO4(6, a6_00, a6_01, a6_10, a6_11)
      CONV_CO4(7, a7_00, a7_01, a7_10, a7_11)
    }
    __syncthreads();
  }

  const int oyA = oy0 + ly2;
  const int oyB = oyA + 1;
  const int ox  = x0 + lx2;
  const bool okA = (oyA < out_y0 + out_rows);
  const bool okB = (oyB < out_y0 + out_rows);

  float acc[8][4] = {
    {a0_00, a0_01, a0_10, a0_11}, {a1_00, a1_01, a1_10, a1_11},
    {a2_00, a2_01, a2_10, a2_11}, {a3_00, a3_01, a3_10, a3_11},
    {a4_00, a4_01, a4_10, a4_11}, {a5_00, a5_01, a5_10, a5_11},
    {a6_00, a6_01, a6_10, a6_11}, {a7_00, a7_01, a7_10, a7_11}};
#pragma unroll
  for (int j = 0; j < 8; j++) {
    float r00 = acc[j][0], r01 = acc[j][1], r10 = acc[j][2], r11 = acc[j][3];
    const int co = co0 + j;
    if constexpr (BNRELU) {
      float s = bn_g[co] * rsqrtf(bn_v[co] + 1e-5f);
      float o = bn_b[co] - bn_m[co] * s;
      r00 = fmaxf(r00 * s + o, 0.f);
      r01 = fmaxf(r01 * s + o, 0.f);
      r10 = fmaxf(r10 * s + o, 0.f);
      r11 = fmaxf(r11 * s + o, 0.f);
    }
    float* base = out + ((size_t)(gi * C_OUT + co) * out_rows) * W_;
    if (okA) { float2 v = {r00, r01}; *(float2*)&base[(size_t)(oyA - out_y0) * W_ + ox] = v; }
    if (okB) { float2 v = {r10, r11}; *(float2*)&base[(size_t)(oyB - out_y0) * W_ + ox] = v; }
  }
}

// ---------------------------------------------------------------------------
// R11: MFMA implicit-GEMM conv for conv2 (32->64) and conv3 (64->24).
// fp32 emulated as f16 hi/lo split: x = hi + lo, A*B ~= Ah*Bh + Ah*Bl + Al*Bh
// (3 MFMAs, fp32 accum) -> rel err ~2^-21, bit-comparable to fp32 conv.
//
// prep_w: split weights once into A-fragment-layout f16 tiles:
//   wb[plane][(t*CICH+c)*9+s][row16][k32], plane 0=hi 1=lo.
//   Lane l of a wave loads 16B at row=(l&15)*64B + (l>>4)*16B -> wave reads a
//   contiguous 1KB tile (fully coalesced, L2-resident).
// ---------------------------------------------------------------------------
template <int C_IN, int C_OUT>
__global__ __launch_bounds__(256) void prep_w(const float* __restrict__ w,
                                              unsigned short* __restrict__ wb)
{
  constexpr int CICH = C_IN / 32;
  constexpr int NCOT = (C_OUT + 15) / 16;
  constexpr int NE = NCOT * CICH * 9 * 512;  // elems per plane
  int i = blockIdx.x * 256 + threadIdx.x;
  if (i >= NE) return;
  int k   = i & 31;
  int row = (i >> 5) & 15;
  int ts  = i >> 9;          // (t*CICH + c)*9 + s
  int s   = ts % 9;
  int tc  = ts / 9;
  int c   = tc % CICH;
  int t   = tc / CICH;
  int co  = t * 16 + row;
  int ci  = c * 32 + k;
  float v = 0.f;
  if (co < C_OUT) v = w[((size_t)co * C_IN + ci) * 9 + s];
  _Float16 h = (_Float16)v;
  _Float16 l = (_Float16)(v - (float)h);
  union { _Float16 f; unsigned short u; } ch, cl;
  ch.f = h; cl.f = l;
  wb[i]      = ch.u;
  wb[NE + i] = cl.u;
}

// Block = 256 thr (4 waves). Output tile: 4 rows x 32 px x C_OUT (all co in
// one block -> input staged ONCE; conv2 FETCH should drop ~287->~110 MB).
// Wave w owns output row w, 2 N-tiles (x 0-15 / 16-31), all NCOT co-tiles.
// LDS: input tile 6 rows x 34 px, channel-last [px][hi32|lo32] f16, pixel
// stride 72 elems = 144 B (== 4 mod 32 banks -> conflict-free ds_read_b128
// B-fragments: every bank serves exactly 8 words per wave read = minimum).
// Staging: register transpose — per (row,px,ci8): 8 coalesced f32 global
// loads (one per ci), cvt to hi/lo f16, two packed ds_write_b128.
// Per block: 864 MFMA (~4300 CU-matrix-pipe cyc) vs ~1700 DS cyc -> MFMA-bound.
// ---------------------------------------------------------------------------
template <int C_IN, int C_OUT, bool BNRELU>
__global__ __launch_bounds__(256, 3) void conv3x3_mfma(
    const float* __restrict__ in, const unsigned short* __restrict__ wb,
    const float* __restrict__ bn_g, const float* __restrict__ bn_b,
    const float* __restrict__ bn_m, const float* __restrict__ bn_v,
    float* __restrict__ out,
    int in_y0, int in_rows, int out_y0, int out_rows)
{
  constexpr int CICH = C_IN / 32;
  constexpr int NCOT = (C_OUT + 15) / 16;
  constexpr int PLANE = NCOT * CICH * 9 * 512;
  constexpr int TXI = 34;   // 32 + 2 halo
  constexpr int PXW = 72;   // 32 hi + 32 lo + 8 pad (f16 elems per pixel)

  __shared__ unsigned short smem[6 * TXI * PXW];  // 29376 B

  const int tilesX = W_ / 32;  // 40
  int bb = blockIdx.x;
  const int txi = bb % tilesX; bb /= tilesX;
  const int tilesY = (out_rows + 3) / 4;
  const int tyi = bb % tilesY;
  const int gi  = bb / tilesY;
  const int x0  = txi * 32;
  const int oy0 = out_y0 + tyi * 4;

  const int tid    = threadIdx.x;
  const int w      = tid >> 6;        // wave id = output row in tile
  const int lane15 = tid & 15;        // pixel-in-Ntile / A row
  const int kgrp   = (tid >> 4) & 3;  // K-group of 8

  f32x4 acc[NCOT][2];
#pragma unroll
  for (int i = 0; i < NCOT; i++) {
    acc[i][0] = (f32x4){0.f, 0.f, 0.f, 0.f};
    acc[i][1] = (f32x4){0.f, 0.f, 0.f, 0.f};
  }

  for (int cc = 0; cc < CICH; ++cc) {
    if (cc) __syncthreads();
    // ---- stage: 6 rows x 34 px x 32 ci (hi/lo), register-transposed ----
    for (int it = tid; it < 816; it += 256) {   // 816 = 4 ci-groups * 204 px
      int cib = it / 204;
      int pos = it - cib * 204;
      int row = pos / 34;
      int px  = pos - row * 34;
      int gy  = oy0 - 1 + row;
      int by  = gy - in_y0;
      int gx  = x0 - 1 + px;
      const bool ok = ((unsigned)by < (unsigned)in_rows) &
                      ((unsigned)gx < (unsigned)W_);
      const float* src =
          in + ((size_t)(gi * C_IN + cc * 32 + cib * 8) * in_rows + by) * (size_t)W_ + gx;
      float v[8];
#pragma unroll
      for (int j = 0; j < 8; j++)
        v[j] = ok ? src[(size_t)j * in_rows * W_] : 0.f;
      union { _Float16 h[8]; uint4 q; } Hq, Lq;
#pragma unroll
      for (int j = 0; j < 8; j++) {
        _Float16 h = (_Float16)v[j];
        Hq.h[j] = h;
        Lq.h[j] = (_Float16)(v[j] - (float)h);
      }
      int base = (row * 34 + px) * PXW + cib * 8;
      *(uint4*)&smem[base]      = Hq.q;   // hi plane: ci in [0,32)
      *(uint4*)&smem[base + 32] = Lq.q;   // lo plane: +32 elems
    }
    __syncthreads();

    // ---- K loop: 9 taps x K=32, 3 split-MFMAs per (co-tile, N-tile) ----
#pragma unroll
    for (int ky = 0; ky < 3; ky++) {
      const int rbase = (w + ky) * TXI;
#pragma unroll
      for (int kx = 0; kx < 3; kx++) {
        const int s  = ky * 3 + kx;
        const int e0 = (rbase + lane15 + kx) * PXW + kgrp * 8;
        f16x8 bh0 = *(const f16x8*)&smem[e0];
        f16x8 bl0 = *(const f16x8*)&smem[e0 + 32];
        f16x8 bh1 = *(const f16x8*)&smem[e0 + 16 * PXW];
        f16x8 bl1 = *(const f16x8*)&smem[e0 + 16 * PXW + 32];
#pragma unroll
        for (int tc = 0; tc < NCOT; tc++) {
          const unsigned short* ap =
              wb + ((size_t)((tc * CICH + cc) * 9 + s) * 512 + lane15 * 32 + kgrp * 8);
          f16x8 ah = *(const f16x8*)ap;
          f16x8 al = *(const f16x8*)(ap + PLANE);
          acc[tc][0] = __builtin_amdgcn_mfma_f32_16x16x32_f16(ah, bh0, acc[tc][0], 0, 0, 0);
          acc[tc][1] = __builtin_amdgcn_mfma_f32_16x16x32_f16(ah, bh1, acc[tc][1], 0, 0, 0);
          acc[tc][0] = __builtin_amdgcn_mfma_f32_16x16x32_f16(al, bh0, acc[tc][0], 0, 0, 0);
          acc[tc][1] = __builtin_amdgcn_mfma_f32_16x16x32_f16(al, bh1, acc[tc][1], 0, 0, 0);
          acc[tc][0] = __builtin_amdgcn_mfma_f32_16x16x32_f16(ah, bl0, acc[tc][0], 0, 0, 0);
          acc[tc][1] = __builtin_amdgcn_mfma_f32_16x16x32_f16(ah, bl1, acc[tc][1], 0, 0, 0);
        }
      }
    }
  }

  // ---- epilogue: D layout col=lane&15 (pixel), row=(lane>>4)*4+j (co) ----
  const int orow = oy0 + w;
  if (orow < out_y0 + out_rows) {
    const int ox = x0 + lane15;
#pragma unroll
    for (int tc = 0; tc < NCOT; tc++) {
#pragma unroll
      for (int j = 0; j < 4; j++) {
        const int co = tc * 16 + kgrp * 4 + j;
        if (co < C_OUT) {
          float r0 = acc[tc][0][j];
          float r1 = acc[tc][1][j];
          if constexpr (BNRELU) {
            float sc = bn_g[co] * rsqrtf(bn_v[co] + 1e-5f);
            float of = bn_b[co] - bn_m[co] * sc;
            r0 = fmaxf(r0 * sc + of, 0.f);
            r1 = fmaxf(r1 * sc + of, 0.f);
          }
          float* bp = out + ((size_t)(gi * C_OUT + co) * out_rows + (orow - out_y0)) * (size_t)W_;
          bp[ox]      = r0;
          bp[ox + 16] = r1;
        }
      }
    }
  }
}

// ---------------------------------------------------------------------------
// Fused propagation epilogue over a band.
// ---------------------------------------------------------------------------
__device__ __forceinline__ float bilin1(const float* __restrict__ img,
                                        float ys, float xs)
{
  float y0f = floorf(ys), x0f = floorf(xs);
  int y0 = (int)y0f, x0 = (int)x0f;
  float wy1 = ys - y0f, wx1 = xs - x0f;
  float wy0 = 1.f - wy1, wx0 = 1.f - wx1;
  int y1 = y0 + 1, x1 = x0 + 1;
  float vy0 = (y0 >= 0 && y0 < H_) ? 1.f : 0.f;
  float vy1 = (y1 >= 0 && y1 < H_) ? 1.f : 0.f;
  float vx0 = (x0 >= 0 && x0 < W_) ? 1.f : 0.f;
  float vx1 = (x1 >= 0 && x1 < W_) ? 1.f : 0.f;
  int yc0 = min(max(y0, 0), H_ - 1), yc1 = min(max(y1, 0), H_ - 1);
  int xc0 = min(max(x0, 0), W_ - 1), xc1 = min(max(x1, 0), W_ - 1);
  const float* r0 = img + (size_t)yc0 * W_;
  const float* r1 = img + (size_t)yc1 * W_;
  float v00 = r0[xc0], v01 = r0[xc1], v10 = r1[xc0], v11 = r1[xc1];
  return (wy0 * vy0) * ((wx0 * vx0) * v00 + (wx1 * vx1) * v01) +
         (wy1 * vy1) * ((wx0 * vx0) * v10 + (wx1 * vx1) * v11);
}

__global__ __launch_bounds__(256) void final_band(
    const float* __restrict__ oa, const float* __restrict__ conf,
    const float* __restrict__ disp, const float* __restrict__ asc,
    float* __restrict__ out, int b0, int g, int y0g, int rows)
{
  int idx = blockIdx.x * 256 + threadIdx.x;
  if (idx >= g * rows * W_) return;
  int x = idx % W_;
  int t = idx / W_;
  int yr = t % rows;
  int gi = t / rows;
  int y = y0g + yr;
  int b = b0 + gi;
  int p = y * W_ + x;

  const float scale = 1.f / (asc[0] + 1e-8f);
  const float* cimg = conf + (size_t)b * HW_;
  const float* dimg = disp + (size_t)b * HW_;
  const float* oab = oa + (size_t)gi * 24 * rows * W_;
  const size_t cs = (size_t)rows * W_;
  const size_t q = (size_t)yr * W_ + x;

  float offy[8], offx[8], a[8];
#pragma unroll
  for (int k = 0; k < 8; k++) {
    offy[k] = oab[(size_t)k * cs + q];
    offx[k] = oab[(size_t)(8 + k) * cs + q];
    float ar = oab[(size_t)(16 + k) * cs + q];
    float ca = bilin1(cimg, (float)y + offy[k], (float)x + offx[k]);
    a[k] = tanhf(ar) * scale * ca;
  }

  float s = 1e-4f;
#pragma unroll
  for (int k = 0; k < 8; k++) s += fabsf(a[k]);
  s = fmaxf(s, 1.f);
  float inv = 1.f / s;
  float suma = 0.f;
#pragma unroll
  for (int k = 0; k < 8; k++) { a[k] *= inv; suma += a[k]; }
  float aref = 1.f - suma;

  float inter = 0.f;
#pragma unroll
  for (int k9 = 0; k9 < 9; k9++) {
    float oy, ox, w;
    if (k9 < 4)       { oy = offy[k9];     ox = offx[k9];     w = a[k9]; }
    else if (k9 == 4) { oy = 0.f;          ox = 0.f;          w = aref;  }
    else              { oy = offy[k9 - 1]; ox = offx[k9 - 1]; w = a[k9 - 1]; }
    float ky = (float)(k9 / 3) - 1.f;
    float kx = (float)(k9 % 3) - 1.f;
    inter += w * bilin1(dimg, (float)y + ky + oy, (float)x + kx + ox);
  }
  inter = fmaxf(inter, 0.f);
  float cd = dimg[p];
  out[(size_t)b * HW_ + p] = fmaxf(0.7f * cd + 0.3f * inter, 0.f);
}

// ---------------------------------------------------------------------------
extern "C" void kernel_launch(void* const* d_in, const int* in_sizes, int n_in,
                              void* d_out, int out_size, void* d_ws, size_t ws_size,
                              hipStream_t stream)
{
  const float* disp   = (const float*)d_in[0];
  const float* normal = (const float*)d_in[1];
  const float* left   = (const float*)d_in[2];
  const float* right  = (const float*)d_in[3];
  const float* conf   = (const float*)d_in[4];
  const float* w1     = (const float*)d_in[5];
  const float* g1     = (const float*)d_in[6];
  const float* b1     = (const float*)d_in[7];
  const float* m1     = (const float*)d_in[8];
  const float* v1     = (const float*)d_in[9];
  const float* w2     = (const float*)d_in[10];
  const float* g2     = (const float*)d_in[11];
  const float* b2     = (const float*)d_in[12];
  const float* m2     = (const float*)d_in[13];
  const float* v2     = (const float*)d_in[14];
  const float* w3     = (const float*)d_in[15];
  const float* asc    = (const float*)d_in[16];
  float* out = (float*)d_out;

  // Split-f16 weight buffers (hi+lo planes), placed after the band buffers.
  constexpr int WB2E = 2 * 4 * 1 * 9 * 512;  // 36864 ushorts (73728 B)
  constexpr int WB3E = 2 * 2 * 2 * 9 * 512;  // 36864 ushorts
  const size_t wbytes = (size_t)(WB2E + WB3E) * sizeof(unsigned short);

  // Band buffers: guid (12ch, bh+6), x1 (32ch, bh+4), x2 (64ch, bh+2).
  // oa (24ch, bh) aliases the ws start (guid+x1 dead by conv3).
  struct Cfg { int g, bh; };
  const Cfg cfgs[] = {{4, 384}, {2, 384}, {1, 384}, {4, 96}, {2, 96},
                      {1, 96}, {1, 48}, {1, 24}, {1, 12}, {1, 8}, {1, 4}};
  int G = 1, BH = 4;
  for (const Cfg& c : cfgs) {
    size_t rows = (size_t)12 * (c.bh + 6) + (size_t)32 * (c.bh + 4) +
                  (size_t)64 * (c.bh + 2);
    size_t need = (size_t)c.g * rows * W_ * sizeof(float) + wbytes;
    if (need <= ws_size) { G = c.g; BH = c.bh; break; }
  }

  float* ws = (float*)d_ws;
  float* guid_buf = ws;
  float* x1_buf   = guid_buf + (size_t)G * 12 * (BH + 6) * W_;
  float* x2_buf   = x1_buf   + (size_t)G * 32 * (BH + 4) * W_;
  float* oa_buf   = ws;  // alias: guid+x1 dead once conv3 runs
  unsigned short* wb2 = (unsigned short*)(x2_buf + (size_t)G * 64 * (BH + 2) * W_);
  unsigned short* wb3 = wb2 + WB2E;

  // One-time weight split (idempotent; cheap — 72 blocks each).
  prep_w<32, 64><<<(WB2E / 2 + 255) / 256, 256, 0, stream>>>(w2, wb2);
  prep_w<64, 24><<<(WB3E / 2 + 255) / 256, 256, 0, stream>>>(w3, wb3);

  const int tilesX = W_ / 32;  // 40

  for (int b0 = 0; b0 < B_; b0 += G) {
    for (int y0 = 0; y0 < H_; y0 += BH) {
      const int rows_out = min(BH, H_ - y0);
      const int y_x2_0 = max(y0 - 1, 0);
      const int y_x2_1 = min(y0 + rows_out + 1, H_);
      const int rows_x2 = y_x2_1 - y_x2_0;
      const int y_x1_0 = max(y0 - 2, 0);
      const int y_x1_1 = min(y0 + rows_out + 2, H_);
      const int rows_x1 = y_x1_1 - y_x1_0;
      const int y_g_0 = max(y0 - 3, 0);
      const int y_g_1 = min(y0 + rows_out + 3, H_);
      const int rows_g = y_g_1 - y_g_0;

      {
        int n = G * rows_g * W_;
        guidance_band<<<(n + 255) / 256, 256, 0, stream>>>(
            disp, normal, left, right, guid_buf, b0, G, y_g_0, rows_g);
      }
      {
        // conv1 12 -> 32 (VALU path): NCO=4, CHUNK=4
        int grid = 4 * tilesX * ((rows_x1 + 31) / 32) * G;
        conv3x3_px4<12, 32, 4, true><<<grid, 256, 0, stream>>>(
            guid_buf, w1, g1, b1, m1, v1, x1_buf,
            y_g_0, rows_g, y_x1_0, rows_x1);
      }
      {
        // conv2 32 -> 64 (MFMA split-f16)
        int grid = tilesX * ((rows_x2 + 3) / 4) * G;
        conv3x3_mfma<32, 64, true><<<grid, 256, 0, stream>>>(
            x1_buf, wb2, g2, b2, m2, v2, x2_buf,
            y_x1_0, rows_x1, y_x2_0, rows_x2);
      }
      {
        // conv3 64 -> 24 (MFMA split-f16, co padded to 32)
        int grid = tilesX * ((rows_out + 3) / 4) * G;
        conv3x3_mfma<64, 24, false><<<grid, 256, 0, stream>>>(
            x2_buf, wb3, nullptr, nullptr, nullptr, nullptr, oa_buf,
            y_x2_0, rows_x2, y0, rows_out);
      }
      {
        int n = G * rows_out * W_;
        final_band<<<(n + 255) / 256, 256, 0, stream>>>(
            oa_buf, conf, disp, asc, out, b0, G, y0, rows_out);
      }
    }
  }
}

// Round 2
// 1154.282 us; speedup vs baseline: 1.8591x; 1.1214x over previous
//
#include <hip/hip_runtime.h>
#include <math.h>

// Problem constants: B=4, H=384, W=1280, NUM=8, IDX_REF=4
static constexpr int B_ = 4;
static constexpr int H_ = 384;
static constexpr int W_ = 1280;
static constexpr int HW_ = H_ * W_;

typedef _Float16 f16x8 __attribute__((ext_vector_type(8)));
typedef float f32x4 __attribute__((ext_vector_type(4)));

// ---------------------------------------------------------------------------
// Guidance band = [normal(3), left(3), right(3), warp(right)-left(3)]
// layout (g, 12, rows, W) covering global rows [y0g, y0g+rows)
// ---------------------------------------------------------------------------
__global__ __launch_bounds__(256) void guidance_band(
    const float* __restrict__ disp, const float* __restrict__ normal,
    const float* __restrict__ left, const float* __restrict__ right,
    float* __restrict__ guid, int b0, int g, int y0g, int rows)
{
  int idx = blockIdx.x * 256 + threadIdx.x;
  if (idx >= g * rows * W_) return;
  int x = idx % W_;
  int t = idx / W_;
  int yr = t % rows;
  int gi = t / rows;
  int y = y0g + yr;
  int b = b0 + gi;
  int p = y * W_ + x;

  float d = disp[(size_t)b * HW_ + p];
  float xs = (float)x - d;
  float x0f = floorf(xs);
  int x0 = (int)x0f;
  float w1 = xs - x0f;
  int xi0 = x0, xi1 = x0 + 1;
  float v0 = (xi0 >= 0 && xi0 < W_) ? 1.f : 0.f;
  float v1 = (xi1 >= 0 && xi1 < W_) ? 1.f : 0.f;
  int xc0 = min(max(xi0, 0), W_ - 1);
  int xc1 = min(max(xi1, 0), W_ - 1);
  float w0f = (1.f - w1) * v0;
  float w1f = w1 * v1;

#pragma unroll
  for (int c = 0; c < 3; c++) {
    const float* rrow = right + (size_t)(b * 3 + c) * HW_ + (size_t)y * W_;
    float l = left[(size_t)(b * 3 + c) * HW_ + p];
    float n = normal[(size_t)(b * 3 + c) * HW_ + p];
    float r = rrow[x];
    float warped = w0f * rrow[xc0] + w1f * rrow[xc1];
    size_t base = ((size_t)gi * 12) * rows * W_ + (size_t)yr * W_ + x;
    size_t cs = (size_t)rows * W_;
    guid[base + (size_t)c * cs]       = n;
    guid[base + (size_t)(3 + c) * cs] = l;
    guid[base + (size_t)(6 + c) * cs] = r;
    guid[base + (size_t)(9 + c) * cs] = warped - l;
  }
}

// ---------------------------------------------------------------------------
// VALU banded 3x3 conv (retained for conv1 only: C_IN=12 is MFMA-K-unfriendly
// and conv1 is ~10% of conv FLOPs).
// ---------------------------------------------------------------------------
#define CONV_CO4(CO, A00, A01, A10, A11)                                       \
  {                                                                            \
    const float* wp = wgt + ((size_t)(co0 + (CO)) * C_IN + ci) * 9;            \
    float w0 = wp[0], w1 = wp[1], w2 = wp[2], w3 = wp[3], w4 = wp[4];          \
    float w5 = wp[5], w6 = wp[6], w7 = wp[7], w8 = wp[8];                      \
    A00 = fmaf(i00, w0, A00); A00 = fmaf(i01, w1, A00); A00 = fmaf(i02, w2, A00); \
    A00 = fmaf(i10, w3, A00); A00 = fmaf(i11, w4, A00); A00 = fmaf(i12, w5, A00); \
    A00 = fmaf(i20, w6, A00); A00 = fmaf(i21, w7, A00); A00 = fmaf(i22, w8, A00); \
    A01 = fmaf(i01, w0, A01); A01 = fmaf(i02, w1, A01); A01 = fmaf(i03, w2, A01); \
    A01 = fmaf(i11, w3, A01); A01 = fmaf(i12, w4, A01); A01 = fmaf(i13, w5, A01); \
    A01 = fmaf(i21, w6, A01); A01 = fmaf(i22, w7, A01); A01 = fmaf(i23, w8, A01); \
    A10 = fmaf(i10, w0, A10); A10 = fmaf(i11, w1, A10); A10 = fmaf(i12, w2, A10); \
    A10 = fmaf(i20, w3, A10); A10 = fmaf(i21, w4, A10); A10 = fmaf(i22, w5, A10); \
    A10 = fmaf(i30, w6, A10); A10 = fmaf(i31, w7, A10); A10 = fmaf(i32, w8, A10); \
    A11 = fmaf(i11, w0, A11); A11 = fmaf(i12, w1, A11); A11 = fmaf(i13, w2, A11); \
    A11 = fmaf(i21, w3, A11); A11 = fmaf(i22, w4, A11); A11 = fmaf(i23, w5, A11); \
    A11 = fmaf(i31, w6, A11); A11 = fmaf(i32, w7, A11); A11 = fmaf(i33, w8, A11); \
  }

template <int C_IN, int C_OUT, int CHUNK, bool BNRELU>
__global__ __launch_bounds__(256, 8) void conv3x3_px4(
    const float* __restrict__ in, const float* __restrict__ wgt,
    const float* __restrict__ bn_g, const float* __restrict__ bn_b,
    const float* __restrict__ bn_m, const float* __restrict__ bn_v,
    float* __restrict__ out,
    int in_y0, int in_rows, int out_y0, int out_rows)
{
  constexpr int TX = 32, TY = 32;
  static_assert(C_IN % CHUNK == 0, "chunking");
  static_assert(C_OUT % 8 == 0, "co tiling");
  constexpr int NCO = C_OUT / 8;
  constexpr int LH = TY + 2;      // 34
  constexpr int LWS = 36;         // 34 used + 2 pad; 16B-aligned rows
  constexpr int QPC = LH * 9;     // 306 quads per channel tile

  __shared__ float smem[CHUNK][LH][LWS];

  const int tilesX = W_ / TX;     // 40
  const int tilesY = (out_rows + TY - 1) / TY;
  int t = blockIdx.x;
  int coi = t % NCO;  t /= NCO;
  int txi = t % tilesX; t /= tilesX;
  int tyi = t % tilesY;
  int gi  = t / tilesY;
  const int x0  = txi * TX;
  const int oy0 = out_y0 + tyi * TY;
  const int co0 = coi * 8;

  const int tid = threadIdx.x;
  const int lx2 = (tid & 15) * 2;
  const int ly2 = (tid >> 4) * 2;

  float a0_00 = 0.f, a0_01 = 0.f, a0_10 = 0.f, a0_11 = 0.f;
  float a1_00 = 0.f, a1_01 = 0.f, a1_10 = 0.f, a1_11 = 0.f;
  float a2_00 = 0.f, a2_01 = 0.f, a2_10 = 0.f, a2_11 = 0.f;
  float a3_00 = 0.f, a3_01 = 0.f, a3_10 = 0.f, a3_11 = 0.f;
  float a4_00 = 0.f, a4_01 = 0.f, a4_10 = 0.f, a4_11 = 0.f;
  float a5_00 = 0.f, a5_01 = 0.f, a5_10 = 0.f, a5_11 = 0.f;
  float a6_00 = 0.f, a6_01 = 0.f, a6_10 = 0.f, a6_11 = 0.f;
  float a7_00 = 0.f, a7_01 = 0.f, a7_10 = 0.f, a7_11 = 0.f;

  for (int c0 = 0; c0 < C_IN; c0 += CHUNK) {
    for (int i = tid; i < CHUNK * QPC; i += 256) {
      int c  = i / QPC;
      int r  = i - c * QPC;
      int yy = r / 9;
      int q  = r - yy * 9;
      int gy = oy0 + yy - 1;
      int by = gy - in_y0;
      int gx = x0 + 4 * q - 1;
      float v0 = 0.f, v1 = 0.f, v2 = 0.f, v3 = 0.f;
      if ((unsigned)by < (unsigned)in_rows) {
        const float* src = in + ((size_t)(gi * C_IN + c0 + c) * in_rows + by) * W_;
        v0 = ((unsigned)(gx + 0) < (unsigned)W_) ? src[gx + 0] : 0.f;
        v1 = ((unsigned)(gx + 1) < (unsigned)W_) ? src[gx + 1] : 0.f;
        v2 = ((unsigned)(gx + 2) < (unsigned)W_) ? src[gx + 2] : 0.f;
        v3 = ((unsigned)(gx + 3) < (unsigned)W_) ? src[gx + 3] : 0.f;
      }
      float* dst = &smem[c][yy][4 * q];
      dst[0] = v0; dst[1] = v1; dst[2] = v2; dst[3] = v3;
    }
    __syncthreads();

    for (int c = 0; c < CHUNK; c++) {
      const float* r0p = &smem[c][ly2 + 0][lx2];
      const float* r1p = &smem[c][ly2 + 1][lx2];
      const float* r2p = &smem[c][ly2 + 2][lx2];
      const float* r3p = &smem[c][ly2 + 3][lx2];
      float2 p00 = *(const float2*)(r0p), p01 = *(const float2*)(r0p + 2);
      float2 p10 = *(const float2*)(r1p), p11 = *(const float2*)(r1p + 2);
      float2 p20 = *(const float2*)(r2p), p21 = *(const float2*)(r2p + 2);
      float2 p30 = *(const float2*)(r3p), p31 = *(const float2*)(r3p + 2);
      float i00 = p00.x, i01 = p00.y, i02 = p01.x, i03 = p01.y;
      float i10 = p10.x, i11 = p10.y, i12 = p11.x, i13 = p11.y;
      float i20 = p20.x, i21 = p20.y, i22 = p21.x, i23 = p21.y;
      float i30 = p30.x, i31 = p30.y, i32 = p31.x, i33 = p31.y;
      const int ci = c0 + c;
      CONV_CO4(0, a0_00, a0_01, a0_10, a0_11)
      CONV_CO4(1, a1_00, a1_01, a1_10, a1_11)
      CONV_CO4(2, a2_00, a2_01, a2_10, a2_11)
      CONV_CO4(3, a3_00, a3_01, a3_10, a3_11)
      CONV_CO4(4, a4_00, a4_01, a4_10, a4_11)
      CONV_CO4(5, a5_00, a5_01, a5_10, a5_11)
      CONV_CO4(6, a6_00, a6_01, a6_10, a6_11)
      CONV_CO4(7, a7_00, a7_01, a7_10, a7_11)
    }
    __syncthreads();
  }

  const int oyA = oy0 + ly2;
  const int oyB = oyA + 1;
  const int ox  = x0 + lx2;
  const bool okA = (oyA < out_y0 + out_rows);
  const bool okB = (oyB < out_y0 + out_rows);

  float acc[8][4] = {
    {a0_00, a0_01, a0_10, a0_11}, {a1_00, a1_01, a1_10, a1_11},
    {a2_00, a2_01, a2_10, a2_11}, {a3_00, a3_01, a3_10, a3_11},
    {a4_00, a4_01, a4_10, a4_11}, {a5_00, a5_01, a5_10, a5_11},
    {a6_00, a6_01, a6_10, a6_11}, {a7_00, a7_01, a7_10, a7_11}};
#pragma unroll
  for (int j = 0; j < 8; j++) {
    float r00 = acc[j][0], r01 = acc[j][1], r10 = acc[j][2], r11 = acc[j][3];
    const int co = co0 + j;
    if constexpr (BNRELU) {
      float s = bn_g[co] * rsqrtf(bn_v[co] + 1e-5f);
      float o = bn_b[co] - bn_m[co] * s;
      r00 = fmaxf(r00 * s + o, 0.f);
      r01 = fmaxf(r01 * s + o, 0.f);
      r10 = fmaxf(r10 * s + o, 0.f);
      r11 = fmaxf(r11 * s + o, 0.f);
    }
    float* base = out + ((size_t)(gi * C_OUT + co) * out_rows) * W_;
    if (okA) { float2 v = {r00, r01}; *(float2*)&base[(size_t)(oyA - out_y0) * W_ + ox] = v; }
    if (okB) { float2 v = {r10, r11}; *(float2*)&base[(size_t)(oyB - out_y0) * W_ + ox] = v; }
  }
}

// ---------------------------------------------------------------------------
// MFMA implicit-GEMM conv (conv2 32->64, conv3 64->24), f16 hi/lo split:
// A*B ~= Ah*Bh + Al*Bh + Ah*Bl (3 MFMAs, fp32 accum, rel err ~2^-21).
//
// prep_w: split weights once into A-fragment-layout f16 tiles:
//   wb[plane][(t*CICH+c)*9+s][row16][k32], plane 0=hi 1=lo.
// ---------------------------------------------------------------------------
template <int C_IN, int C_OUT>
__global__ __launch_bounds__(256) void prep_w(const float* __restrict__ w,
                                              unsigned short* __restrict__ wb)
{
  constexpr int CICH = C_IN / 32;
  constexpr int NCOT = (C_OUT + 15) / 16;
  constexpr int NE = NCOT * CICH * 9 * 512;  // elems per plane
  int i = blockIdx.x * 256 + threadIdx.x;
  if (i >= NE) return;
  int k   = i & 31;
  int row = (i >> 5) & 15;
  int ts  = i >> 9;          // (t*CICH + c)*9 + s
  int s   = ts % 9;
  int tc  = ts / 9;
  int c   = tc % CICH;
  int t   = tc / CICH;
  int co  = t * 16 + row;
  int ci  = c * 32 + k;
  float v = 0.f;
  if (co < C_OUT) v = w[((size_t)co * C_IN + ci) * 9 + s];
  _Float16 h = (_Float16)v;
  _Float16 l = (_Float16)(v - (float)h);
  union { _Float16 f; unsigned short u; } ch, cl;
  ch.f = h; cl.f = l;
  wb[i]      = ch.u;
  wb[NE + i] = cl.u;
}

// R12: TY=8 output rows per block (halo ratio 1.25 vs 1.5), wave w owns rows
// {2w, 2w+1} -> 432 MFMA/wave between barriers; A-frags reused across 2 rows.
// Explicit next-tap A-register prefetch (R11 diagnosis: compiler kept only
// 52 VGPR -> zero loads in flight -> MfmaUtil 18% with all pipes <25%).
// MFMA order hh -> lh -> hl so al/bl consumers trail their loads.
// LDS: 10 rows x 36 px (cols rebased to x0-2 so staging loads are float2-
// aligned) x PXW=72 f16 (32 hi | 32 lo | 8 pad); 51840 B.
// ---------------------------------------------------------------------------
template <int C_IN, int C_OUT, bool BNRELU>
__global__ __launch_bounds__(256, (C_IN == 32 ? 2 : 3)) void conv3x3_mfma(
    const float* __restrict__ in, const unsigned short* __restrict__ wb,
    const float* __restrict__ bn_g, const float* __restrict__ bn_b,
    const float* __restrict__ bn_m, const float* __restrict__ bn_v,
    float* __restrict__ out,
    int in_y0, int in_rows, int out_y0, int out_rows)
{
  constexpr int CICH = C_IN / 32;
  constexpr int NCOT = (C_OUT + 15) / 16;
  constexpr int PLANE = NCOT * CICH * 9 * 512;
  constexpr int TY  = 8;    // output rows per block
  constexpr int HR  = 10;   // staged rows (TY + 2 halo)
  constexpr int TXI = 36;   // staged cols: x0-2 .. x0+33 (col c <-> gx = x0-2+c)
  constexpr int PX2 = 18;   // float2 columns per row
  constexpr int PXW = 72;   // 32 hi + 32 lo + 8 pad (f16 per pixel)

  __shared__ unsigned short smem[HR * TXI * PXW];  // 51840 B

  const int tilesX = W_ / 32;  // 40
  int bb = blockIdx.x;
  const int txi = bb % tilesX; bb /= tilesX;
  const int tilesY = (out_rows + TY - 1) / TY;
  const int tyi = bb % tilesY;
  const int gi  = bb / tilesY;
  const int x0  = txi * 32;
  const int oy0 = out_y0 + tyi * TY;

  const int tid    = threadIdx.x;
  const int w      = tid >> 6;        // wave id: owns output rows 2w, 2w+1
  const int lane15 = tid & 15;        // pixel-in-Ntile / A row
  const int kgrp   = (tid >> 4) & 3;  // K-group of 8
  const int aoff   = lane15 * 32 + kgrp * 8;

  f32x4 acc[NCOT][2][2];  // [co-tile][row rr][N-tile]
#pragma unroll
  for (int i = 0; i < NCOT; i++)
#pragma unroll
    for (int rr = 0; rr < 2; rr++) {
      acc[i][rr][0] = (f32x4){0.f, 0.f, 0.f, 0.f};
      acc[i][rr][1] = (f32x4){0.f, 0.f, 0.f, 0.f};
    }

  for (int cc = 0; cc < CICH; ++cc) {
    if (cc) __syncthreads();
    // ---- stage: HR rows x 36 px x 32 ci (hi/lo), float2 + reg transpose ----
    for (int it = tid; it < 4 * HR * PX2; it += 256) {   // 720 items
      int cib = it / (HR * PX2);
      int pos = it - cib * (HR * PX2);
      int row = pos / PX2;
      int p2  = pos - row * PX2;
      int gy  = oy0 - 1 + row;
      int by  = gy - in_y0;
      int gx  = x0 - 2 + 2 * p2;
      const bool rok = (unsigned)by < (unsigned)in_rows;
      const bool ok0 = rok & ((unsigned)gx < (unsigned)W_);
      const bool ok1 = rok & ((unsigned)(gx + 1) < (unsigned)W_);
      const float* src =
          in + ((size_t)(gi * C_IN + cc * 32 + cib * 8) * in_rows + by) * (size_t)W_ + gx;
      float v0[8], v1[8];
#pragma unroll
      for (int j = 0; j < 8; j++) {
        const float* cp = src + (size_t)j * in_rows * W_;
        float2 tv = {0.f, 0.f};
        if (ok0 & ok1) tv = *(const float2*)cp;
        else { if (ok0) tv.x = cp[0]; if (ok1) tv.y = cp[1]; }
        v0[j] = tv.x; v1[j] = tv.y;
      }
      union { _Float16 h[8]; uint4 q; } H0, L0, H1, L1;
#pragma unroll
      for (int j = 0; j < 8; j++) {
        _Float16 h0 = (_Float16)v0[j];
        H0.h[j] = h0; L0.h[j] = (_Float16)(v0[j] - (float)h0);
        _Float16 h1 = (_Float16)v1[j];
        H1.h[j] = h1; L1.h[j] = (_Float16)(v1[j] - (float)h1);
      }
      int base = (row * TXI + 2 * p2) * PXW + cib * 8;
      *(uint4*)&smem[base]            = H0.q;
      *(uint4*)&smem[base + 32]       = L0.q;
      *(uint4*)&smem[base + PXW]      = H1.q;
      *(uint4*)&smem[base + PXW + 32] = L1.q;
    }
    __syncthreads();

    // ---- K loop: 9 taps; A prefetched one tap ahead; hh -> lh -> hl ----
    f16x8 ah[NCOT], al[NCOT];
#pragma unroll
    for (int tc = 0; tc < NCOT; tc++) {
      const unsigned short* ap =
          wb + ((size_t)((tc * CICH + cc) * 9 + 0) * 512 + aoff);
      ah[tc] = *(const f16x8*)ap;
      al[tc] = *(const f16x8*)(ap + PLANE);
    }
#pragma unroll
    for (int s = 0; s < 9; s++) {
      const int ky = s / 3, kx = s - 3 * ky;
      // B fragments for both rows, both N-tiles (col 1+lane15+kx maps gx)
      f16x8 bh[2][2], bl[2][2];
#pragma unroll
      for (int rr = 0; rr < 2; rr++) {
        const int e0 = ((2 * w + rr + ky) * TXI + 1 + lane15 + kx) * PXW + kgrp * 8;
        bh[rr][0] = *(const f16x8*)&smem[e0];
        bl[rr][0] = *(const f16x8*)&smem[e0 + 32];
        bh[rr][1] = *(const f16x8*)&smem[e0 + 16 * PXW];
        bl[rr][1] = *(const f16x8*)&smem[e0 + 16 * PXW + 32];
      }
      // prefetch next tap's A fragments
      f16x8 ahn[NCOT], aln[NCOT];
      if (s < 8) {
#pragma unroll
        for (int tc = 0; tc < NCOT; tc++) {
          const unsigned short* ap =
              wb + ((size_t)((tc * CICH + cc) * 9 + s + 1) * 512 + aoff);
          ahn[tc] = *(const f16x8*)ap;
          aln[tc] = *(const f16x8*)(ap + PLANE);
        }
      }
      // MFMAs: Ah*Bh first (A ready), then Al*Bh, then Ah*Bl
#pragma unroll
      for (int tc = 0; tc < NCOT; tc++)
#pragma unroll
        for (int rr = 0; rr < 2; rr++)
#pragma unroll
          for (int nt = 0; nt < 2; nt++)
            acc[tc][rr][nt] = __builtin_amdgcn_mfma_f32_16x16x32_f16(
                ah[tc], bh[rr][nt], acc[tc][rr][nt], 0, 0, 0);
#pragma unroll
      for (int tc = 0; tc < NCOT; tc++)
#pragma unroll
        for (int rr = 0; rr < 2; rr++)
#pragma unroll
          for (int nt = 0; nt < 2; nt++)
            acc[tc][rr][nt] = __builtin_amdgcn_mfma_f32_16x16x32_f16(
                al[tc], bh[rr][nt], acc[tc][rr][nt], 0, 0, 0);
#pragma unroll
      for (int tc = 0; tc < NCOT; tc++)
#pragma unroll
        for (int rr = 0; rr < 2; rr++)
#pragma unroll
          for (int nt = 0; nt < 2; nt++)
            acc[tc][rr][nt] = __builtin_amdgcn_mfma_f32_16x16x32_f16(
                ah[tc], bl[rr][nt], acc[tc][rr][nt], 0, 0, 0);
      if (s < 8) {
#pragma unroll
        for (int tc = 0; tc < NCOT; tc++) { ah[tc] = ahn[tc]; al[tc] = aln[tc]; }
      }
    }
  }

  // ---- epilogue: D layout col=lane&15 (pixel), row=kgrp*4+j (co) ----
#pragma unroll
  for (int rr = 0; rr < 2; rr++) {
    const int orow = oy0 + 2 * w + rr;
    if (orow < out_y0 + out_rows) {
      const int ox = x0 + lane15;
#pragma unroll
      for (int tc = 0; tc < NCOT; tc++) {
#pragma unroll
        for (int j = 0; j < 4; j++) {
          const int co = tc * 16 + kgrp * 4 + j;
          if (co < C_OUT) {
            float r0 = acc[tc][rr][0][j];
            float r1 = acc[tc][rr][1][j];
            if constexpr (BNRELU) {
              float sc = bn_g[co] * rsqrtf(bn_v[co] + 1e-5f);
              float of = bn_b[co] - bn_m[co] * sc;
              r0 = fmaxf(r0 * sc + of, 0.f);
              r1 = fmaxf(r1 * sc + of, 0.f);
            }
            float* bp = out + ((size_t)(gi * C_OUT + co) * out_rows +
                               (orow - out_y0)) * (size_t)W_;
            bp[ox]      = r0;
            bp[ox + 16] = r1;
          }
        }
      }
    }
  }
}

// ---------------------------------------------------------------------------
// Fused propagation epilogue over a band.
// ---------------------------------------------------------------------------
__device__ __forceinline__ float bilin1(const float* __restrict__ img,
                                        float ys, float xs)
{
  float y0f = floorf(ys), x0f = floorf(xs);
  int y0 = (int)y0f, x0 = (int)x0f;
  float wy1 = ys - y0f, wx1 = xs - x0f;
  float wy0 = 1.f - wy1, wx0 = 1.f - wx1;
  int y1 = y0 + 1, x1 = x0 + 1;
  float vy0 = (y0 >= 0 && y0 < H_) ? 1.f : 0.f;
  float vy1 = (y1 >= 0 && y1 < H_) ? 1.f : 0.f;
  float vx0 = (x0 >= 0 && x0 < W_) ? 1.f : 0.f;
  float vx1 = (x1 >= 0 && x1 < W_) ? 1.f : 0.f;
  int yc0 = min(max(y0, 0), H_ - 1), yc1 = min(max(y1, 0), H_ - 1);
  int xc0 = min(max(x0, 0), W_ - 1), xc1 = min(max(x1, 0), W_ - 1);
  const float* r0 = img + (size_t)yc0 * W_;
  const float* r1 = img + (size_t)yc1 * W_;
  float v00 = r0[xc0], v01 = r0[xc1], v10 = r1[xc0], v11 = r1[xc1];
  return (wy0 * vy0) * ((wx0 * vx0) * v00 + (wx1 * vx1) * v01) +
         (wy1 * vy1) * ((wx0 * vx0) * v10 + (wx1 * vx1) * v11);
}

__global__ __launch_bounds__(256) void final_band(
    const float* __restrict__ oa, const float* __restrict__ conf,
    const float* __restrict__ disp, const float* __restrict__ asc,
    float* __restrict__ out, int b0, int g, int y0g, int rows)
{
  int idx = blockIdx.x * 256 + threadIdx.x;
  if (idx >= g * rows * W_) return;
  int x = idx % W_;
  int t = idx / W_;
  int yr = t % rows;
  int gi = t / rows;
  int y = y0g + yr;
  int b = b0 + gi;
  int p = y * W_ + x;

  const float scale = 1.f / (asc[0] + 1e-8f);
  const float* cimg = conf + (size_t)b * HW_;
  const float* dimg = disp + (size_t)b * HW_;
  const float* oab = oa + (size_t)gi * 24 * rows * W_;
  const size_t cs = (size_t)rows * W_;
  const size_t q = (size_t)yr * W_ + x;

  float offy[8], offx[8], a[8];
#pragma unroll
  for (int k = 0; k < 8; k++) {
    offy[k] = oab[(size_t)k * cs + q];
    offx[k] = oab[(size_t)(8 + k) * cs + q];
    float ar = oab[(size_t)(16 + k) * cs + q];
    float ca = bilin1(cimg, (float)y + offy[k], (float)x + offx[k]);
    a[k] = tanhf(ar) * scale * ca;
  }

  float s = 1e-4f;
#pragma unroll
  for (int k = 0; k < 8; k++) s += fabsf(a[k]);
  s = fmaxf(s, 1.f);
  float inv = 1.f / s;
  float suma = 0.f;
#pragma unroll
  for (int k = 0; k < 8; k++) { a[k] *= inv; suma += a[k]; }
  float aref = 1.f - suma;

  float inter = 0.f;
#pragma unroll
  for (int k9 = 0; k9 < 9; k9++) {
    float oy, ox, w;
    if (k9 < 4)       { oy = offy[k9];     ox = offx[k9];     w = a[k9]; }
    else if (k9 == 4) { oy = 0.f;          ox = 0.f;          w = aref;  }
    else              { oy = offy[k9 - 1]; ox = offx[k9 - 1]; w = a[k9 - 1]; }
    float ky = (float)(k9 / 3) - 1.f;
    float kx = (float)(k9 % 3) - 1.f;
    inter += w * bilin1(dimg, (float)y + ky + oy, (float)x + kx + ox);
  }
  inter = fmaxf(inter, 0.f);
  float cd = dimg[p];
  out[(size_t)b * HW_ + p] = fmaxf(0.7f * cd + 0.3f * inter, 0.f);
}

// ---------------------------------------------------------------------------
extern "C" void kernel_launch(void* const* d_in, const int* in_sizes, int n_in,
                              void* d_out, int out_size, void* d_ws, size_t ws_size,
                              hipStream_t stream)
{
  const float* disp   = (const float*)d_in[0];
  const float* normal = (const float*)d_in[1];
  const float* left   = (const float*)d_in[2];
  const float* right  = (const float*)d_in[3];
  const float* conf   = (const float*)d_in[4];
  const float* w1     = (const float*)d_in[5];
  const float* g1     = (const float*)d_in[6];
  const float* b1     = (const float*)d_in[7];
  const float* m1     = (const float*)d_in[8];
  const float* v1     = (const float*)d_in[9];
  const float* w2     = (const float*)d_in[10];
  const float* g2     = (const float*)d_in[11];
  const float* b2     = (const float*)d_in[12];
  const float* m2     = (const float*)d_in[13];
  const float* v2     = (const float*)d_in[14];
  const float* w3     = (const float*)d_in[15];
  const float* asc    = (const float*)d_in[16];
  float* out = (float*)d_out;

  // Split-f16 weight buffers (hi+lo planes), placed after the band buffers.
  constexpr int WB2E = 2 * 4 * 1 * 9 * 512;  // 36864 ushorts (73728 B)
  constexpr int WB3E = 2 * 2 * 2 * 9 * 512;  // 36864 ushorts
  const size_t wbytes = (size_t)(WB2E + WB3E) * sizeof(unsigned short);

  // Band buffers: guid (12ch, bh+6), x1 (32ch, bh+4), x2 (64ch, bh+2).
  // oa (24ch, bh) aliases the ws start (guid+x1 dead by conv3).
  struct Cfg { int g, bh; };
  const Cfg cfgs[] = {{4, 384}, {2, 384}, {1, 384}, {4, 96}, {2, 96},
                      {1, 96}, {1, 48}, {1, 24}, {1, 12}, {1, 8}, {1, 4}};
  int G = 1, BH = 4;
  for (const Cfg& c : cfgs) {
    size_t rows = (size_t)12 * (c.bh + 6) + (size_t)32 * (c.bh + 4) +
                  (size_t)64 * (c.bh + 2);
    size_t need = (size_t)c.g * rows * W_ * sizeof(float) + wbytes;
    if (need <= ws_size) { G = c.g; BH = c.bh; break; }
  }

  float* ws = (float*)d_ws;
  float* guid_buf = ws;
  float* x1_buf   = guid_buf + (size_t)G * 12 * (BH + 6) * W_;
  float* x2_buf   = x1_buf   + (size_t)G * 32 * (BH + 4) * W_;
  float* oa_buf   = ws;  // alias: guid+x1 dead once conv3 runs
  unsigned short* wb2 = (unsigned short*)(x2_buf + (size_t)G * 64 * (BH + 2) * W_);
  unsigned short* wb3 = wb2 + WB2E;

  // One-time weight split (idempotent; cheap).
  prep_w<32, 64><<<(WB2E / 2 + 255) / 256, 256, 0, stream>>>(w2, wb2);
  prep_w<64, 24><<<(WB3E / 2 + 255) / 256, 256, 0, stream>>>(w3, wb3);

  const int tilesX = W_ / 32;  // 40

  for (int b0 = 0; b0 < B_; b0 += G) {
    for (int y0 = 0; y0 < H_; y0 += BH) {
      const int rows_out = min(BH, H_ - y0);
      const int y_x2_0 = max(y0 - 1, 0);
      const int y_x2_1 = min(y0 + rows_out + 1, H_);
      const int rows_x2 = y_x2_1 - y_x2_0;
      const int y_x1_0 = max(y0 - 2, 0);
      const int y_x1_1 = min(y0 + rows_out + 2, H_);
      const int rows_x1 = y_x1_1 - y_x1_0;
      const int y_g_0 = max(y0 - 3, 0);
      const int y_g_1 = min(y0 + rows_out + 3, H_);
      const int rows_g = y_g_1 - y_g_0;

      {
        int n = G * rows_g * W_;
        guidance_band<<<(n + 255) / 256, 256, 0, stream>>>(
            disp, normal, left, right, guid_buf, b0, G, y_g_0, rows_g);
      }
      {
        // conv1 12 -> 32 (VALU path): NCO=4, CHUNK=4
        int grid = 4 * tilesX * ((rows_x1 + 31) / 32) * G;
        conv3x3_px4<12, 32, 4, true><<<grid, 256, 0, stream>>>(
            guid_buf, w1, g1, b1, m1, v1, x1_buf,
            y_g_0, rows_g, y_x1_0, rows_x1);
      }
      {
        // conv2 32 -> 64 (MFMA split-f16, TY=8)
        int grid = tilesX * ((rows_x2 + 7) / 8) * G;
        conv3x3_mfma<32, 64, true><<<grid, 256, 0, stream>>>(
            x1_buf, wb2, g2, b2, m2, v2, x2_buf,
            y_x1_0, rows_x1, y_x2_0, rows_x2);
      }
      {
        // conv3 64 -> 24 (MFMA split-f16, TY=8, co padded to 32)
        int grid = tilesX * ((rows_out + 7) / 8) * G;
        conv3x3_mfma<64, 24, false><<<grid, 256, 0, stream>>>(
            x2_buf, wb3, nullptr, nullptr, nullptr, nullptr, oa_buf,
            y_x2_0, rows_x2, y0, rows_out);
      }
      {
        int n = G * rows_out * W_;
        final_band<<<(n + 255) / 256, 256, 0, stream>>>(
            oa_buf, conf, disp, asc, out, b0, G, y0, rows_out);
      }
    }
  }
}

// Round 3
// 1109.256 us; speedup vs baseline: 1.9346x; 1.0406x over previous
//
#include <hip/hip_runtime.h>
#include <math.h>

// Problem constants: B=4, H=384, W=1280, NUM=8, IDX_REF=4
static constexpr int B_ = 4;
static constexpr int H_ = 384;
static constexpr int W_ = 1280;
static constexpr int HW_ = H_ * W_;

typedef _Float16 f16x8 __attribute__((ext_vector_type(8)));
typedef float f32x4 __attribute__((ext_vector_type(4)));

// ---------------------------------------------------------------------------
// Split-f16 activation layout ("s16"): per octet of channels (ci/8), per
// pixel: 8 f16 hi then 8 f16 lo (32 B records). Same bytes as f32 planes.
// x = hi + lo with hi=(f16)x, lo=(f16)(x-hi) -> A*B via AhBh+AlBh+AhBl MFMAs
// has rel err ~2^-21 (bit-comparable to fp32 conv). Split is computed ONCE
// at the producer (R3: R2's per-stage split was ~1440 VALU-cyc/block, on the
// serial path of a 23%-MfmaUtil latency-bound kernel).
// ---------------------------------------------------------------------------

// ---------------------------------------------------------------------------
// Guidance band = [normal(3), left(3), right(3), warp(right)-left(3)]
// layout (g, 12, rows, W) covering global rows [y0g, y0g+rows)
// ---------------------------------------------------------------------------
__global__ __launch_bounds__(256) void guidance_band(
    const float* __restrict__ disp, const float* __restrict__ normal,
    const float* __restrict__ left, const float* __restrict__ right,
    float* __restrict__ guid, int b0, int g, int y0g, int rows)
{
  int idx = blockIdx.x * 256 + threadIdx.x;
  if (idx >= g * rows * W_) return;
  int x = idx % W_;
  int t = idx / W_;
  int yr = t % rows;
  int gi = t / rows;
  int y = y0g + yr;
  int b = b0 + gi;
  int p = y * W_ + x;

  float d = disp[(size_t)b * HW_ + p];
  float xs = (float)x - d;
  float x0f = floorf(xs);
  int x0 = (int)x0f;
  float w1 = xs - x0f;
  int xi0 = x0, xi1 = x0 + 1;
  float v0 = (xi0 >= 0 && xi0 < W_) ? 1.f : 0.f;
  float v1 = (xi1 >= 0 && xi1 < W_) ? 1.f : 0.f;
  int xc0 = min(max(xi0, 0), W_ - 1);
  int xc1 = min(max(xi1, 0), W_ - 1);
  float w0f = (1.f - w1) * v0;
  float w1f = w1 * v1;

#pragma unroll
  for (int c = 0; c < 3; c++) {
    const float* rrow = right + (size_t)(b * 3 + c) * HW_ + (size_t)y * W_;
    float l = left[(size_t)(b * 3 + c) * HW_ + p];
    float n = normal[(size_t)(b * 3 + c) * HW_ + p];
    float r = rrow[x];
    float warped = w0f * rrow[xc0] + w1f * rrow[xc1];
    size_t base = ((size_t)gi * 12) * rows * W_ + (size_t)yr * W_ + x;
    size_t cs = (size_t)rows * W_;
    guid[base + (size_t)c * cs]       = n;
    guid[base + (size_t)(3 + c) * cs] = l;
    guid[base + (size_t)(6 + c) * cs] = r;
    guid[base + (size_t)(9 + c) * cs] = warped - l;
  }
}

// ---------------------------------------------------------------------------
// VALU banded 3x3 conv (conv1 only: C_IN=12 is MFMA-K-unfriendly, ~10% of
// conv FLOPs). R3: epilogue now emits split-f16 records for conv2's stage.
// ---------------------------------------------------------------------------
#define CONV_CO4(CO, A00, A01, A10, A11)                                       \
  {                                                                            \
    const float* wp = wgt + ((size_t)(co0 + (CO)) * C_IN + ci) * 9;            \
    float w0 = wp[0], w1 = wp[1], w2 = wp[2], w3 = wp[3], w4 = wp[4];          \
    float w5 = wp[5], w6 = wp[6], w7 = wp[7], w8 = wp[8];                      \
    A00 = fmaf(i00, w0, A00); A00 = fmaf(i01, w1, A00); A00 = fmaf(i02, w2, A00); \
    A00 = fmaf(i10, w3, A00); A00 = fmaf(i11, w4, A00); A00 = fmaf(i12, w5, A00); \
    A00 = fmaf(i20, w6, A00); A00 = fmaf(i21, w7, A00); A00 = fmaf(i22, w8, A00); \
    A01 = fmaf(i01, w0, A01); A01 = fmaf(i02, w1, A01); A01 = fmaf(i03, w2, A01); \
    A01 = fmaf(i11, w3, A01); A01 = fmaf(i12, w4, A01); A01 = fmaf(i13, w5, A01); \
    A01 = fmaf(i21, w6, A01); A01 = fmaf(i22, w7, A01); A01 = fmaf(i23, w8, A01); \
    A10 = fmaf(i10, w0, A10); A10 = fmaf(i11, w1, A10); A10 = fmaf(i12, w2, A10); \
    A10 = fmaf(i20, w3, A10); A10 = fmaf(i21, w4, A10); A10 = fmaf(i22, w5, A10); \
    A10 = fmaf(i30, w6, A10); A10 = fmaf(i31, w7, A10); A10 = fmaf(i32, w8, A10); \
    A11 = fmaf(i11, w0, A11); A11 = fmaf(i12, w1, A11); A11 = fmaf(i13, w2, A11); \
    A11 = fmaf(i21, w3, A11); A11 = fmaf(i22, w4, A11); A11 = fmaf(i23, w5, A11); \
    A11 = fmaf(i31, w6, A11); A11 = fmaf(i32, w7, A11); A11 = fmaf(i33, w8, A11); \
  }

template <int C_IN, int C_OUT, int CHUNK>
__global__ __launch_bounds__(256, 8) void conv3x3_px4(
    const float* __restrict__ in, const float* __restrict__ wgt,
    const float* __restrict__ bn_g, const float* __restrict__ bn_b,
    const float* __restrict__ bn_m, const float* __restrict__ bn_v,
    unsigned short* __restrict__ out,   // split-f16 octet records
    int in_y0, int in_rows, int out_y0, int out_rows)
{
  constexpr int TX = 32, TY = 32;
  static_assert(C_IN % CHUNK == 0, "chunking");
  static_assert(C_OUT % 8 == 0, "co tiling");
  constexpr int NCO = C_OUT / 8;
  constexpr int LH = TY + 2;      // 34
  constexpr int LWS = 36;         // 34 used + 2 pad; 16B-aligned rows
  constexpr int QPC = LH * 9;     // 306 quads per channel tile

  __shared__ float smem[CHUNK][LH][LWS];

  const int tilesX = W_ / TX;     // 40
  const int tilesY = (out_rows + TY - 1) / TY;
  int t = blockIdx.x;
  int coi = t % NCO;  t /= NCO;
  int txi = t % tilesX; t /= tilesX;
  int tyi = t % tilesY;
  int gi  = t / tilesY;
  const int x0  = txi * TX;
  const int oy0 = out_y0 + tyi * TY;
  const int co0 = coi * 8;

  const int tid = threadIdx.x;
  const int lx2 = (tid & 15) * 2;
  const int ly2 = (tid >> 4) * 2;

  float a0_00 = 0.f, a0_01 = 0.f, a0_10 = 0.f, a0_11 = 0.f;
  float a1_00 = 0.f, a1_01 = 0.f, a1_10 = 0.f, a1_11 = 0.f;
  float a2_00 = 0.f, a2_01 = 0.f, a2_10 = 0.f, a2_11 = 0.f;
  float a3_00 = 0.f, a3_01 = 0.f, a3_10 = 0.f, a3_11 = 0.f;
  float a4_00 = 0.f, a4_01 = 0.f, a4_10 = 0.f, a4_11 = 0.f;
  float a5_00 = 0.f, a5_01 = 0.f, a5_10 = 0.f, a5_11 = 0.f;
  float a6_00 = 0.f, a6_01 = 0.f, a6_10 = 0.f, a6_11 = 0.f;
  float a7_00 = 0.f, a7_01 = 0.f, a7_10 = 0.f, a7_11 = 0.f;

  for (int c0 = 0; c0 < C_IN; c0 += CHUNK) {
    for (int i = tid; i < CHUNK * QPC; i += 256) {
      int c  = i / QPC;
      int r  = i - c * QPC;
      int yy = r / 9;
      int q  = r - yy * 9;
      int gy = oy0 + yy - 1;
      int by = gy - in_y0;
      int gx = x0 + 4 * q - 1;
      float v0 = 0.f, v1 = 0.f, v2 = 0.f, v3 = 0.f;
      if ((unsigned)by < (unsigned)in_rows) {
        const float* src = in + ((size_t)(gi * C_IN + c0 + c) * in_rows + by) * W_;
        v0 = ((unsigned)(gx + 0) < (unsigned)W_) ? src[gx + 0] : 0.f;
        v1 = ((unsigned)(gx + 1) < (unsigned)W_) ? src[gx + 1] : 0.f;
        v2 = ((unsigned)(gx + 2) < (unsigned)W_) ? src[gx + 2] : 0.f;
        v3 = ((unsigned)(gx + 3) < (unsigned)W_) ? src[gx + 3] : 0.f;
      }
      float* dst = &smem[c][yy][4 * q];
      dst[0] = v0; dst[1] = v1; dst[2] = v2; dst[3] = v3;
    }
    __syncthreads();

    for (int c = 0; c < CHUNK; c++) {
      const float* r0p = &smem[c][ly2 + 0][lx2];
      const float* r1p = &smem[c][ly2 + 1][lx2];
      const float* r2p = &smem[c][ly2 + 2][lx2];
      const float* r3p = &smem[c][ly2 + 3][lx2];
      float2 p00 = *(const float2*)(r0p), p01 = *(const float2*)(r0p + 2);
      float2 p10 = *(const float2*)(r1p), p11 = *(const float2*)(r1p + 2);
      float2 p20 = *(const float2*)(r2p), p21 = *(const float2*)(r2p + 2);
      float2 p30 = *(const float2*)(r3p), p31 = *(const float2*)(r3p + 2);
      float i00 = p00.x, i01 = p00.y, i02 = p01.x, i03 = p01.y;
      float i10 = p10.x, i11 = p10.y, i12 = p11.x, i13 = p11.y;
      float i20 = p20.x, i21 = p20.y, i22 = p21.x, i23 = p21.y;
      float i30 = p30.x, i31 = p30.y, i32 = p31.x, i33 = p31.y;
      const int ci = c0 + c;
      CONV_CO4(0, a0_00, a0_01, a0_10, a0_11)
      CONV_CO4(1, a1_00, a1_01, a1_10, a1_11)
      CONV_CO4(2, a2_00, a2_01, a2_10, a2_11)
      CONV_CO4(3, a3_00, a3_01, a3_10, a3_11)
      CONV_CO4(4, a4_00, a4_01, a4_10, a4_11)
      CONV_CO4(5, a5_00, a5_01, a5_10, a5_11)
      CONV_CO4(6, a6_00, a6_01, a6_10, a6_11)
      CONV_CO4(7, a7_00, a7_01, a7_10, a7_11)
    }
    __syncthreads();
  }

  const int oyA = oy0 + ly2;
  const int oyB = oyA + 1;
  const int ox  = x0 + lx2;
  const bool okA = (oyA < out_y0 + out_rows);
  const bool okB = (oyB < out_y0 + out_rows);

  float acc[8][4] = {
    {a0_00, a0_01, a0_10, a0_11}, {a1_00, a1_01, a1_10, a1_11},
    {a2_00, a2_01, a2_10, a2_11}, {a3_00, a3_01, a3_10, a3_11},
    {a4_00, a4_01, a4_10, a4_11}, {a5_00, a5_01, a5_10, a5_11},
    {a6_00, a6_01, a6_10, a6_11}, {a7_00, a7_01, a7_10, a7_11}};

  // BN + ReLU, then split-f16 pack: per pixel, 8 co (one octet) -> 32 B rec.
  float sc[8], of[8];
#pragma unroll
  for (int j = 0; j < 8; j++) {
    float s = bn_g[co0 + j] * rsqrtf(bn_v[co0 + j] + 1e-5f);
    sc[j] = s;
    of[j] = bn_b[co0 + j] - bn_m[co0 + j] * s;
  }
#pragma unroll
  for (int q = 0; q < 4; q++) {
    const bool ok = (q < 2) ? okA : okB;
    if (!ok) continue;
    const int oy = (q < 2) ? oyA : oyB;
    const int px = ox + (q & 1);
    union { _Float16 f[8]; uint4 u; } Hh, Ll;
#pragma unroll
    for (int j = 0; j < 8; j++) {
      float v = fmaxf(acc[j][q] * sc[j] + of[j], 0.f);
      _Float16 h = (_Float16)v;
      Hh.f[j] = h;
      Ll.f[j] = (_Float16)(v - (float)h);
    }
    size_t rec = (((size_t)(gi * NCO + coi) * out_rows + (oy - out_y0)) * W_ + px) * 16;
    *(uint4*)&out[rec]     = Hh.u;
    *(uint4*)&out[rec + 8] = Ll.u;
  }
}

// ---------------------------------------------------------------------------
// MFMA implicit-GEMM conv (conv2 32->64, conv3 64->24), split-f16 inputs.
//
// prep_w: split weights once into A-fragment-layout f16 tiles:
//   wb[plane][(t*CICH+c)*9+s][row16][k32], plane 0=hi 1=lo.
// ---------------------------------------------------------------------------
template <int C_IN, int C_OUT>
__global__ __launch_bounds__(256) void prep_w(const float* __restrict__ w,
                                              unsigned short* __restrict__ wb)
{
  constexpr int CICH = C_IN / 32;
  constexpr int NCOT = (C_OUT + 15) / 16;
  constexpr int NE = NCOT * CICH * 9 * 512;  // elems per plane
  int i = blockIdx.x * 256 + threadIdx.x;
  if (i >= NE) return;
  int k   = i & 31;
  int row = (i >> 5) & 15;
  int ts  = i >> 9;          // (t*CICH + c)*9 + s
  int s   = ts % 9;
  int tc  = ts / 9;
  int c   = tc % CICH;
  int t   = tc / CICH;
  int co  = t * 16 + row;
  int ci  = c * 32 + k;
  float v = 0.f;
  if (co < C_OUT) v = w[((size_t)co * C_IN + ci) * 9 + s];
  _Float16 h = (_Float16)v;
  _Float16 l = (_Float16)(v - (float)h);
  union { _Float16 f; unsigned short u; } ch, cl;
  ch.f = h; cl.f = l;
  wb[i]      = ch.u;
  wb[NE + i] = cl.u;
}

// R12 structure (TY=8, wave owns 2 rows, A-prefetch, hh->lh->hl) with R3's
// copy-only stage: input already split-f16 in octet records, so staging is
// 4 uint4 global loads + 4 ds_write_b128 per item — no cvt math.
// LDS: 10 rows x 36 px x PXW=72 f16 (32 hi | 32 lo | 8 pad); 51840 B
// -> 3 blocks/CU. B-read px stride 144 B == 16 B mod 128 -> 2-way (free).
// ---------------------------------------------------------------------------
template <int C_IN, int C_OUT, bool BNRELU, bool OSPLIT>
__global__ __launch_bounds__(256, (C_IN == 32 ? 2 : 3)) void conv3x3_mfma(
    const unsigned short* __restrict__ in, const unsigned short* __restrict__ wb,
    const float* __restrict__ bn_g, const float* __restrict__ bn_b,
    const float* __restrict__ bn_m, const float* __restrict__ bn_v,
    void* __restrict__ out,
    int in_y0, int in_rows, int out_y0, int out_rows)
{
  constexpr int CICH = C_IN / 32;
  constexpr int NCIO = C_IN / 8;    // input octets
  constexpr int NCOT = (C_OUT + 15) / 16;
  constexpr int PLANE = NCOT * CICH * 9 * 512;
  constexpr int TY  = 8;    // output rows per block
  constexpr int HR  = 10;   // staged rows (TY + 2 halo)
  constexpr int TXI = 36;   // staged cols: x0-2 .. x0+33
  constexpr int PX2 = 18;   // pixel pairs per row
  constexpr int PXW = 72;   // 32 hi + 32 lo + 8 pad (f16 per pixel)

  __shared__ unsigned short smem[HR * TXI * PXW];  // 51840 B

  const int tilesX = W_ / 32;  // 40
  int bb = blockIdx.x;
  const int txi = bb % tilesX; bb /= tilesX;
  const int tilesY = (out_rows + TY - 1) / TY;
  const int tyi = bb % tilesY;
  const int gi  = bb / tilesY;
  const int x0  = txi * 32;
  const int oy0 = out_y0 + tyi * TY;

  const int tid    = threadIdx.x;
  const int w      = tid >> 6;        // wave id: owns output rows 2w, 2w+1
  const int lane15 = tid & 15;        // pixel-in-Ntile / A row
  const int kgrp   = (tid >> 4) & 3;  // K-group of 8
  const int aoff   = lane15 * 32 + kgrp * 8;

  f32x4 acc[NCOT][2][2];  // [co-tile][row rr][N-tile]
#pragma unroll
  for (int i = 0; i < NCOT; i++)
#pragma unroll
    for (int rr = 0; rr < 2; rr++) {
      acc[i][rr][0] = (f32x4){0.f, 0.f, 0.f, 0.f};
      acc[i][rr][1] = (f32x4){0.f, 0.f, 0.f, 0.f};
    }

  for (int cc = 0; cc < CICH; ++cc) {
    if (cc) __syncthreads();
    // ---- stage: pure copy of split-f16 records (2 px = 64 B per item) ----
    for (int it = tid; it < 4 * HR * PX2; it += 256) {   // 720 items
      int cib = it / (HR * PX2);
      int pos = it - cib * (HR * PX2);
      int row = pos / PX2;
      int p2  = pos - row * PX2;
      int gy  = oy0 - 1 + row;
      int by  = gy - in_y0;
      int gx  = x0 - 2 + 2 * p2;
      const bool rok = (unsigned)by < (unsigned)in_rows;
      uint4 h0 = {0,0,0,0}, l0 = {0,0,0,0}, h1 = {0,0,0,0}, l1 = {0,0,0,0};
      const unsigned short* src =
          in + (((size_t)(gi * NCIO + cc * 4 + cib) * in_rows + by) * W_ + gx) * 16;
      if (rok & ((unsigned)gx < (unsigned)W_)) {
        h0 = *(const uint4*)(src);
        l0 = *(const uint4*)(src + 8);
      }
      if (rok & ((unsigned)(gx + 1) < (unsigned)W_)) {
        h1 = *(const uint4*)(src + 16);
        l1 = *(const uint4*)(src + 24);
      }
      int base = (row * TXI + 2 * p2) * PXW + cib * 8;
      *(uint4*)&smem[base]            = h0;
      *(uint4*)&smem[base + 32]       = l0;
      *(uint4*)&smem[base + PXW]      = h1;
      *(uint4*)&smem[base + PXW + 32] = l1;
    }
    __syncthreads();

    // ---- K loop: 9 taps; A prefetched one tap ahead; hh -> lh -> hl ----
    f16x8 ah[NCOT], al[NCOT];
#pragma unroll
    for (int tc = 0; tc < NCOT; tc++) {
      const unsigned short* ap =
          wb + ((size_t)((tc * CICH + cc) * 9 + 0) * 512 + aoff);
      ah[tc] = *(const f16x8*)ap;
      al[tc] = *(const f16x8*)(ap + PLANE);
    }
#pragma unroll
    for (int s = 0; s < 9; s++) {
      const int ky = s / 3, kx = s - 3 * ky;
      f16x8 bh[2][2], bl[2][2];
#pragma unroll
      for (int rr = 0; rr < 2; rr++) {
        const int e0 = ((2 * w + rr + ky) * TXI + 1 + lane15 + kx) * PXW + kgrp * 8;
        bh[rr][0] = *(const f16x8*)&smem[e0];
        bl[rr][0] = *(const f16x8*)&smem[e0 + 32];
        bh[rr][1] = *(const f16x8*)&smem[e0 + 16 * PXW];
        bl[rr][1] = *(const f16x8*)&smem[e0 + 16 * PXW + 32];
      }
      f16x8 ahn[NCOT], aln[NCOT];
      if (s < 8) {
#pragma unroll
        for (int tc = 0; tc < NCOT; tc++) {
          const unsigned short* ap =
              wb + ((size_t)((tc * CICH + cc) * 9 + s + 1) * 512 + aoff);
          ahn[tc] = *(const f16x8*)ap;
          aln[tc] = *(const f16x8*)(ap + PLANE);
        }
      }
#pragma unroll
      for (int tc = 0; tc < NCOT; tc++)
#pragma unroll
        for (int rr = 0; rr < 2; rr++)
#pragma unroll
          for (int nt = 0; nt < 2; nt++)
            acc[tc][rr][nt] = __builtin_amdgcn_mfma_f32_16x16x32_f16(
                ah[tc], bh[rr][nt], acc[tc][rr][nt], 0, 0, 0);
#pragma unroll
      for (int tc = 0; tc < NCOT; tc++)
#pragma unroll
        for (int rr = 0; rr < 2; rr++)
#pragma unroll
          for (int nt = 0; nt < 2; nt++)
            acc[tc][rr][nt] = __builtin_amdgcn_mfma_f32_16x16x32_f16(
                al[tc], bh[rr][nt], acc[tc][rr][nt], 0, 0, 0);
#pragma unroll
      for (int tc = 0; tc < NCOT; tc++)
#pragma unroll
        for (int rr = 0; rr < 2; rr++)
#pragma unroll
          for (int nt = 0; nt < 2; nt++)
            acc[tc][rr][nt] = __builtin_amdgcn_mfma_f32_16x16x32_f16(
                ah[tc], bl[rr][nt], acc[tc][rr][nt], 0, 0, 0);
      if (s < 8) {
#pragma unroll
        for (int tc = 0; tc < NCOT; tc++) { ah[tc] = ahn[tc]; al[tc] = aln[tc]; }
      }
    }
  }

  // ---- epilogue: D layout col=lane&15 (pixel), row=kgrp*4+j (co) ----
#pragma unroll
  for (int rr = 0; rr < 2; rr++) {
    const int orow = oy0 + 2 * w + rr;
    if (orow < out_y0 + out_rows) {
      const int ox = x0 + lane15;
      if constexpr (OSPLIT) {
        // split-f16 records: octet o = tc*2 + (kgrp>>1), half = kgrp&1
        unsigned short* outs = (unsigned short*)out;
#pragma unroll
        for (int tc = 0; tc < NCOT; tc++) {
          const int o = tc * 2 + (kgrp >> 1);
          const size_t recbase =
              (((size_t)(gi * (C_OUT / 8) + o) * out_rows + (orow - out_y0)) * W_ + ox) * 16
              + (kgrp & 1) * 4;
#pragma unroll
          for (int nt = 0; nt < 2; nt++) {
            union { _Float16 f[4]; uint2 u; } Hh, Ll;
#pragma unroll
            for (int j = 0; j < 4; j++) {
              float v = acc[tc][rr][nt][j];
              if constexpr (BNRELU) {
                const int co = tc * 16 + kgrp * 4 + j;
                float s = bn_g[co] * rsqrtf(bn_v[co] + 1e-5f);
                v = fmaxf(v * s + (bn_b[co] - bn_m[co] * s), 0.f);
              }
              _Float16 h = (_Float16)v;
              Hh.f[j] = h;
              Ll.f[j] = (_Float16)(v - (float)h);
            }
            const size_t rec = recbase + (size_t)nt * 256;  // +16 px
            *(uint2*)&outs[rec]     = Hh.u;
            *(uint2*)&outs[rec + 8] = Ll.u;
          }
        }
      } else {
        float* outf = (float*)out;
#pragma unroll
        for (int tc = 0; tc < NCOT; tc++) {
#pragma unroll
          for (int j = 0; j < 4; j++) {
            const int co = tc * 16 + kgrp * 4 + j;
            if (co < C_OUT) {
              float r0 = acc[tc][rr][0][j];
              float r1 = acc[tc][rr][1][j];
              if constexpr (BNRELU) {
                float sc = bn_g[co] * rsqrtf(bn_v[co] + 1e-5f);
                float of = bn_b[co] - bn_m[co] * sc;
                r0 = fmaxf(r0 * sc + of, 0.f);
                r1 = fmaxf(r1 * sc + of, 0.f);
              }
              float* bp = outf + ((size_t)(gi * C_OUT + co) * out_rows +
                                  (orow - out_y0)) * (size_t)W_;
              bp[ox]      = r0;
              bp[ox + 16] = r1;
            }
          }
        }
      }
    }
  }
}

// ---------------------------------------------------------------------------
// Fused propagation epilogue over a band.
// ---------------------------------------------------------------------------
__device__ __forceinline__ float bilin1(const float* __restrict__ img,
                                        float ys, float xs)
{
  float y0f = floorf(ys), x0f = floorf(xs);
  int y0 = (int)y0f, x0 = (int)x0f;
  float wy1 = ys - y0f, wx1 = xs - x0f;
  float wy0 = 1.f - wy1, wx0 = 1.f - wx1;
  int y1 = y0 + 1, x1 = x0 + 1;
  float vy0 = (y0 >= 0 && y0 < H_) ? 1.f : 0.f;
  float vy1 = (y1 >= 0 && y1 < H_) ? 1.f : 0.f;
  float vx0 = (x0 >= 0 && x0 < W_) ? 1.f : 0.f;
  float vx1 = (x1 >= 0 && x1 < W_) ? 1.f : 0.f;
  int yc0 = min(max(y0, 0), H_ - 1), yc1 = min(max(y1, 0), H_ - 1);
  int xc0 = min(max(x0, 0), W_ - 1), xc1 = min(max(x1, 0), W_ - 1);
  const float* r0 = img + (size_t)yc0 * W_;
  const float* r1 = img + (size_t)yc1 * W_;
  float v00 = r0[xc0], v01 = r0[xc1], v10 = r1[xc0], v11 = r1[xc1];
  return (wy0 * vy0) * ((wx0 * vx0) * v00 + (wx1 * vx1) * v01) +
         (wy1 * vy1) * ((wx0 * vx0) * v10 + (wx1 * vx1) * v11);
}

__global__ __launch_bounds__(256) void final_band(
    const float* __restrict__ oa, const float* __restrict__ conf,
    const float* __restrict__ disp, const float* __restrict__ asc,
    float* __restrict__ out, int b0, int g, int y0g, int rows)
{
  int idx = blockIdx.x * 256 + threadIdx.x;
  if (idx >= g * rows * W_) return;
  int x = idx % W_;
  int t = idx / W_;
  int yr = t % rows;
  int gi = t / rows;
  int y = y0g + yr;
  int b = b0 + gi;
  int p = y * W_ + x;

  const float scale = 1.f / (asc[0] + 1e-8f);
  const float* cimg = conf + (size_t)b * HW_;
  const float* dimg = disp + (size_t)b * HW_;
  const float* oab = oa + (size_t)gi * 24 * rows * W_;
  const size_t cs = (size_t)rows * W_;
  const size_t q = (size_t)yr * W_ + x;

  float offy[8], offx[8], a[8];
#pragma unroll
  for (int k = 0; k < 8; k++) {
    offy[k] = oab[(size_t)k * cs + q];
    offx[k] = oab[(size_t)(8 + k) * cs + q];
    float ar = oab[(size_t)(16 + k) * cs + q];
    float ca = bilin1(cimg, (float)y + offy[k], (float)x + offx[k]);
    a[k] = tanhf(ar) * scale * ca;
  }

  float s = 1e-4f;
#pragma unroll
  for (int k = 0; k < 8; k++) s += fabsf(a[k]);
  s = fmaxf(s, 1.f);
  float inv = 1.f / s;
  float suma = 0.f;
#pragma unroll
  for (int k = 0; k < 8; k++) { a[k] *= inv; suma += a[k]; }
  float aref = 1.f - suma;

  float inter = 0.f;
#pragma unroll
  for (int k9 = 0; k9 < 9; k9++) {
    float oy, ox, w;
    if (k9 < 4)       { oy = offy[k9];     ox = offx[k9];     w = a[k9]; }
    else if (k9 == 4) { oy = 0.f;          ox = 0.f;          w = aref;  }
    else              { oy = offy[k9 - 1]; ox = offx[k9 - 1]; w = a[k9 - 1]; }
    float ky = (float)(k9 / 3) - 1.f;
    float kx = (float)(k9 % 3) - 1.f;
    inter += w * bilin1(dimg, (float)y + ky + oy, (float)x + kx + ox);
  }
  inter = fmaxf(inter, 0.f);
  float cd = dimg[p];
  out[(size_t)b * HW_ + p] = fmaxf(0.7f * cd + 0.3f * inter, 0.f);
}

// ---------------------------------------------------------------------------
extern "C" void kernel_launch(void* const* d_in, const int* in_sizes, int n_in,
                              void* d_out, int out_size, void* d_ws, size_t ws_size,
                              hipStream_t stream)
{
  const float* disp   = (const float*)d_in[0];
  const float* normal = (const float*)d_in[1];
  const float* left   = (const float*)d_in[2];
  const float* right  = (const float*)d_in[3];
  const float* conf   = (const float*)d_in[4];
  const float* w1     = (const float*)d_in[5];
  const float* g1     = (const float*)d_in[6];
  const float* b1     = (const float*)d_in[7];
  const float* m1     = (const float*)d_in[8];
  const float* v1     = (const float*)d_in[9];
  const float* w2     = (const float*)d_in[10];
  const float* g2     = (const float*)d_in[11];
  const float* b2     = (const float*)d_in[12];
  const float* m2     = (const float*)d_in[13];
  const float* v2     = (const float*)d_in[14];
  const float* w3     = (const float*)d_in[15];
  const float* asc    = (const float*)d_in[16];
  float* out = (float*)d_out;

  // Split-f16 weight buffers (hi+lo planes), placed after the band buffers.
  constexpr int WB2E = 2 * 4 * 1 * 9 * 512;  // 36864 ushorts (73728 B)
  constexpr int WB3E = 2 * 2 * 2 * 9 * 512;  // 36864 ushorts
  const size_t wbytes = (size_t)(WB2E + WB3E) * sizeof(unsigned short);

  // Band buffers: guid (12ch f32, bh+6), x1s (32ch split-f16, bh+4 — same
  // bytes as f32), x2s (64ch split-f16, bh+2 — same bytes), oa (24ch f32, bh)
  // aliases the ws start (guid+x1s dead by conv3).
  struct Cfg { int g, bh; };
  const Cfg cfgs[] = {{4, 384}, {2, 384}, {1, 384}, {4, 96}, {2, 96},
                      {1, 96}, {1, 48}, {1, 24}, {1, 12}, {1, 8}, {1, 4}};
  int G = 1, BH = 4;
  for (const Cfg& c : cfgs) {
    size_t rows = (size_t)12 * (c.bh + 6) + (size_t)32 * (c.bh + 4) +
                  (size_t)64 * (c.bh + 2);
    size_t need = (size_t)c.g * rows * W_ * sizeof(float) + wbytes;
    if (need <= ws_size) { G = c.g; BH = c.bh; break; }
  }

  float* ws = (float*)d_ws;
  float* guid_buf = ws;
  unsigned short* x1s = (unsigned short*)(guid_buf + (size_t)G * 12 * (BH + 6) * W_);
  unsigned short* x2s = x1s + (size_t)G * 64 * (BH + 4) * W_;   // 32ch*2planes f16
  float* oa_buf = ws;  // alias: guid+x1s dead once conv3 runs
  unsigned short* wb2 = x2s + (size_t)G * 128 * (BH + 2) * W_;  // 64ch*2planes f16
  unsigned short* wb3 = wb2 + WB2E;

  // One-time weight split (idempotent; cheap).
  prep_w<32, 64><<<(WB2E / 2 + 255) / 256, 256, 0, stream>>>(w2, wb2);
  prep_w<64, 24><<<(WB3E / 2 + 255) / 256, 256, 0, stream>>>(w3, wb3);

  const int tilesX = W_ / 32;  // 40

  for (int b0 = 0; b0 < B_; b0 += G) {
    for (int y0 = 0; y0 < H_; y0 += BH) {
      const int rows_out = min(BH, H_ - y0);
      const int y_x2_0 = max(y0 - 1, 0);
      const int y_x2_1 = min(y0 + rows_out + 1, H_);
      const int rows_x2 = y_x2_1 - y_x2_0;
      const int y_x1_0 = max(y0 - 2, 0);
      const int y_x1_1 = min(y0 + rows_out + 2, H_);
      const int rows_x1 = y_x1_1 - y_x1_0;
      const int y_g_0 = max(y0 - 3, 0);
      const int y_g_1 = min(y0 + rows_out + 3, H_);
      const int rows_g = y_g_1 - y_g_0;

      {
        int n = G * rows_g * W_;
        guidance_band<<<(n + 255) / 256, 256, 0, stream>>>(
            disp, normal, left, right, guid_buf, b0, G, y_g_0, rows_g);
      }
      {
        // conv1 12 -> 32 (VALU path, split-f16 output): NCO=4, CHUNK=4
        int grid = 4 * tilesX * ((rows_x1 + 31) / 32) * G;
        conv3x3_px4<12, 32, 4><<<grid, 256, 0, stream>>>(
            guid_buf, w1, g1, b1, m1, v1, x1s,
            y_g_0, rows_g, y_x1_0, rows_x1);
      }
      {
        // conv2 32 -> 64 (MFMA, split-f16 in/out, TY=8)
        int grid = tilesX * ((rows_x2 + 7) / 8) * G;
        conv3x3_mfma<32, 64, true, true><<<grid, 256, 0, stream>>>(
            x1s, wb2, g2, b2, m2, v2, (void*)x2s,
            y_x1_0, rows_x1, y_x2_0, rows_x2);
      }
      {
        // conv3 64 -> 24 (MFMA, split-f16 in, f32 out, TY=8)
        int grid = tilesX * ((rows_out + 7) / 8) * G;
        conv3x3_mfma<64, 24, false, false><<<grid, 256, 0, stream>>>(
            x2s, wb3, nullptr, nullptr, nullptr, nullptr, (void*)oa_buf,
            y_x2_0, rows_x2, y0, rows_out);
      }
      {
        int n = G * rows_out * W_;
        final_band<<<(n + 255) / 256, 256, 0, stream>>>(
            oa_buf, conf, disp, asc, out, b0, G, y0, rows_out);
      }
    }
  }
}